// Round 1
// baseline (612.621 us; speedup 1.0000x reference)
//
#include <hip/hip_runtime.h>
#include <cstdint>
#include <cstddef>

typedef __bf16 bf16x8v __attribute__((ext_vector_type(8)));
typedef float f32x4v __attribute__((ext_vector_type(4)));

// async global->LDS, 16B per lane; LDS dest is wave-uniform base (HW adds lane*16)
__device__ __forceinline__ void gload_lds16(const void* g, void* l) {
  __builtin_amdgcn_global_load_lds((const __attribute__((address_space(1))) void*)g,
                                   (__attribute__((address_space(3))) void*)l,
                                   16, 0, 0);
}

__device__ __forceinline__ bf16x8v cvt_bf16x8(f32x4v a, f32x4v b) {
  bf16x8v r;
  r[0] = (__bf16)a[0]; r[1] = (__bf16)a[1]; r[2] = (__bf16)a[2]; r[3] = (__bf16)a[3];
  r[4] = (__bf16)b[0]; r[5] = (__bf16)b[1]; r[6] = (__bf16)b[2]; r[7] = (__bf16)b[3];
  return r;
}

// ---------------- prep: toep bf16 [1024,1024] + Wcat bf16 [128,1024] -------------------
__global__ __launch_bounds__(256) void prep_kernel(const float* __restrict__ W1,
                                                   const float* __restrict__ Wslope,
                                                   const float* __restrict__ Wint,
                                                   __bf16* __restrict__ toep,
                                                   __bf16* __restrict__ Wcat) {
  int id = blockIdx.x * 256 + threadIdx.x;
  if (id < 1024 * 1024) {
    int i = id >> 10, j = id & 1023;
    int p = 1023 - i + j;
    float v = (p < 1024) ? W1[(size_t)(1023 - p) << 10] : W1[p - 1023];
    toep[id] = (__bf16)v;
  } else {
    int id2 = id - 1024 * 1024;
    int n = id2 >> 10, k = id2 & 1023;
    float v = (n < 64) ? Wslope[((size_t)n << 10) + k] : Wint[((size_t)(n - 64) << 10) + k];
    Wcat[id2] = (__bf16)v;
  }
}

// ---------------- GEMM1: q = relu([x|h] @ toep^T + b1), fp32-A DMA, bf16 out ----------
// 128x128 tile, BK=32, dbuf DMA, XCD-swizzled grid.
// A staged as FP32 straight from x/h (pack kernel eliminated); cvt->bf16 at frag load.
// Both A and B LDS tiles use source-preswizzled 16B slots (slot ^= row & (nslots-1))
// so ds_read_b128 frag loads spread across bank groups instead of 8/16-way conflicts.
__global__ __launch_bounds__(256) void gemm1_f32dma(const float* __restrict__ x,
                                                    const float* __restrict__ h,
                                                    const __bf16* __restrict__ toep,
                                                    const float* __restrict__ b1,
                                                    __bf16* __restrict__ q) {
  __shared__ __align__(16) float  Af[2][128 * 32];   // 16 KB each (fp32, 8 slots/row)
  __shared__ __align__(16) __bf16 Bf[2][128 * 32];   // 8 KB each (bf16, 4 slots/row)
  const int tid = threadIdx.x, wid = tid >> 6, lane = tid & 63;
  const int wrow = wid >> 1, wcol = wid & 1;
  // XCD swizzle: XCD x gets m-tiles {x, 8+x, ...}, each m-tile's 8 n-tiles consecutive
  // -> A-rows (L2) and the 2 MB toep stay resident in that XCD's 4 MB L2.
  const int bid = blockIdx.x;
  const int xcd = bid & 7, j = bid >> 3;
  const int m0 = (((j >> 3) << 3) | xcd) << 7;   // m-tile 0..511
  const int n0 = (j & 7) << 7;                   // n-tile 0..7
  const int quad = lane >> 4, l15 = lane & 15;
  // A DMA mapping: fp32, 4 floats (16B) per lane, 8 lanes/row, 8 rows/instr
  const int rl8 = lane >> 3, s8 = lane & 7;
  const int sA = s8 ^ rl8;                       // swizzled global slot (row&7 == rl8)
  // B DMA mapping: bf16, 8 elems (16B) per lane, 4 lanes/row, 16 rows/instr
  const int rl4 = lane >> 2, s4 = lane & 3;
  const int sB = s4 ^ (rl4 & 3);                 // swizzled global slot (row&3)

  f32x4v acc[4][4] = {};

  const int arow = m0 + wid * 32;                // wave's A-stage base row
  const __bf16* gB = toep + (((size_t)(n0 + wid * 32 + rl4)) << 10) + sB * 8;
  const size_t BROW16 = (size_t)16 << 10;

  auto stageA = [&](float* la, int kt) {
    const int k0 = kt << 5;
    const float* src;
    int rstride;
    if (k0 < 64) { src = x + (size_t)(arow + rl8) * 64 + k0 + sA * 4;        rstride = 8 * 64; }
    else         { src = h + (size_t)(arow + rl8) * 960 + (k0 - 64) + sA * 4; rstride = 8 * 960; }
    const int rb = wid * 32;
#pragma unroll
    for (int i = 0; i < 4; ++i) {
      gload_lds16(src, &la[(rb + i * 8) * 32]);
      src += rstride;
    }
  };
  auto stageB = [&](__bf16* lb) {
    const int rb = wid * 32;
    gload_lds16(gB,          &lb[rb * 32]);
    gload_lds16(gB + BROW16, &lb[(rb + 16) * 32]);
    gB += 32;
  };

  auto compute = [&](const float* la, const __bf16* lb) {
    bf16x8v af[4], bfr[4];
#pragma unroll
    for (int r = 0; r < 4; ++r) {
      const int row = wrow * 64 + r * 16 + l15;
      const f32x4v* base = (const f32x4v*)&la[row * 32];
      f32x4v lo = base[(quad * 2)     ^ (row & 7)];
      f32x4v hi = base[(quad * 2 + 1) ^ (row & 7)];
      af[r] = cvt_bf16x8(lo, hi);
    }
#pragma unroll
    for (int c = 0; c < 4; ++c) {
      const int row = wcol * 64 + c * 16 + l15;
      const bf16x8v* bb = (const bf16x8v*)&lb[row * 32];
      bfr[c] = bb[quad ^ (row & 3)];
    }
#pragma unroll
    for (int r = 0; r < 4; ++r)
#pragma unroll
      for (int c = 0; c < 4; ++c)
        acc[r][c] = __builtin_amdgcn_mfma_f32_16x16x32_bf16(af[r], bfr[c], acc[r][c], 0, 0, 0);
  };

  stageA(Af[0], 0); stageB(Bf[0]);               // kt = 0
  for (int kt = 0; kt < 32; kt += 2) {
    __syncthreads();                             // drains DMA into buf0; guards buf1 reuse
    stageA(Af[1], kt + 1); stageB(Bf[1]);        // kt+1 (always <= 31)
    compute(Af[0], Bf[0]);
    __syncthreads();                             // drains DMA into buf1; guards buf0 reuse
    if (kt < 30) { stageA(Af[0], kt + 2); stageB(Bf[0]); }  // kt+2
    compute(Af[1], Bf[1]);
  }

  // epilogue: C/D col=lane&15, row=quad*4+e
#pragma unroll
  for (int c = 0; c < 4; ++c) {
    int col = n0 + wcol * 64 + c * 16 + l15;
    float bias = b1[col];
#pragma unroll
    for (int r = 0; r < 4; ++r)
#pragma unroll
      for (int e = 0; e < 4; ++e) {
        int row = m0 + wrow * 64 + r * 16 + quad * 4 + e;
        q[((size_t)row << 10) + col] = (__bf16)fmaxf(acc[r][c][e] + bias, 0.0f);
      }
  }
}

// ---------------- GEMM2: [slope|intercept] = act(q @ Wcat^T + bias) -------------------
// 64-row tiles (1024 blocks), BK=64, dbuf DMA; wave tile 32x64.
// LDS tiles have 128B rows -> row drops out of the bank index; same source-preswizzle
// (8 slots/row, slot ^= row&7) to kill the 16-way ds_read_b128 conflicts.
__global__ __launch_bounds__(256) void gemm2_dma(const __bf16* __restrict__ q,
                                                 const __bf16* __restrict__ Wcat,
                                                 const float* __restrict__ b_slope,
                                                 const float* __restrict__ b_int,
                                                 float* __restrict__ out) {
  __shared__ __align__(16) __bf16 Ab[2][64 * 64];
  __shared__ __align__(16) __bf16 Bb[2][128 * 64];
  const int tid = threadIdx.x, wid = tid >> 6, lane = tid & 63;
  const int wrow = wid >> 1, wcol = wid & 1;
  const int m0 = blockIdx.x << 6;
  const int quad = lane >> 4, l15 = lane & 15;
  const int r8 = lane >> 3, s8 = lane & 7;    // DMA: 8 lanes/row (128B rows), 8 rows/instr
  const int sw = (s8 ^ r8) * 8;               // swizzled global element offset

  f32x4v acc[2][4] = {};

  auto stage = [&](int buf, int kt) {
    int k0 = kt << 6;
#pragma unroll
    for (int j2 = 0; j2 < 2; ++j2) {
      int rb = wid * 16 + j2 * 8;
      gload_lds16(q + (((size_t)(m0 + rb + r8)) << 10) + k0 + sw, &Ab[buf][rb * 64]);
    }
#pragma unroll
    for (int j2 = 0; j2 < 4; ++j2) {
      int rb = wid * 32 + j2 * 8;
      gload_lds16(Wcat + (((size_t)(rb + r8)) << 10) + k0 + sw, &Bb[buf][rb * 64]);
    }
  };

  stage(0, 0);
  for (int kt = 0; kt < 16; ++kt) {
    int cur = kt & 1;
    __syncthreads();
    if (kt < 15) stage(cur ^ 1, kt + 1);
#pragma unroll
    for (int s = 0; s < 2; ++s) {
      bf16x8v af[2], bfr[4];
#pragma unroll
      for (int r = 0; r < 2; ++r) {
        const int row = wrow * 32 + r * 16 + l15;
        af[r] = *(const bf16x8v*)&Ab[cur][row * 64 + (((s * 4 + quad) ^ (row & 7)) * 8)];
      }
#pragma unroll
      for (int c = 0; c < 4; ++c) {
        const int row = wcol * 64 + c * 16 + l15;
        bfr[c] = *(const bf16x8v*)&Bb[cur][row * 64 + (((s * 4 + quad) ^ (row & 7)) * 8)];
      }
#pragma unroll
      for (int r = 0; r < 2; ++r)
#pragma unroll
        for (int c = 0; c < 4; ++c)
          acc[r][c] = __builtin_amdgcn_mfma_f32_16x16x32_bf16(af[r], bfr[c], acc[r][c], 0, 0, 0);
    }
  }

#pragma unroll
  for (int c = 0; c < 4; ++c) {
    int col = wcol * 64 + c * 16 + l15;       // col<64 is wave-uniform (wcol)
    float bias = (col < 64) ? b_slope[col] : b_int[col - 64];
#pragma unroll
    for (int r = 0; r < 2; ++r)
#pragma unroll
      for (int e = 0; e < 4; ++e) {
        int row = m0 + wrow * 32 + r * 16 + quad * 4 + e;
        float v = acc[r][c][e] + bias;
        if (col < 64) {
          float xc = fminf(fmaxf(v, -15.f), 15.f);
          float t = __expf(2.f * xc);
          out[(size_t)row * 64 + col] = (t - 1.f) / (t + 1.f);   // tanh
        } else {
          out[(size_t)4194304 + (size_t)row * 64 + (col - 64)] = v;
        }
      }
  }
}

extern "C" void kernel_launch(void* const* d_in, const int* in_sizes, int n_in,
                              void* d_out, int out_size, void* d_ws, size_t ws_size,
                              hipStream_t stream) {
  const float* x  = (const float*)d_in[0];
  const float* h  = (const float*)d_in[1];
  const float* W1 = (const float*)d_in[2];
  const float* b1 = (const float*)d_in[3];
  const float* Ws = (const float*)d_in[4];
  const float* bs = (const float*)d_in[5];
  const float* Wi = (const float*)d_in[6];
  const float* bi = (const float*)d_in[7];
  char* ws = (char*)d_ws;

  const size_t SZ_Q    = 134217728;   // q    bf16 [65536,1024]
  const size_t SZ_TOEP = 2097152;     // toep bf16 [1024,1024]

  __bf16* q    = (__bf16*)ws;
  __bf16* toep = (__bf16*)(ws + SZ_Q);
  __bf16* Wcat = (__bf16*)(ws + SZ_Q + SZ_TOEP);

  hipLaunchKernelGGL(prep_kernel,  dim3(4608), dim3(256), 0, stream, W1, Ws, Wi, toep, Wcat);
  hipLaunchKernelGGL(gemm1_f32dma, dim3(4096), dim3(256), 0, stream, x, h, toep, b1, q);
  hipLaunchKernelGGL(gemm2_dma,    dim3(1024), dim3(256), 0, stream, q, Wcat, bs, bi,
                     (float*)d_out);
}

// Round 2
// 602.797 us; speedup vs baseline: 1.0163x; 1.0163x over previous
//
#include <hip/hip_runtime.h>
#include <cstdint>
#include <cstddef>

typedef __bf16 bf16x8v __attribute__((ext_vector_type(8)));
typedef float f32x4v __attribute__((ext_vector_type(4)));

// async global->LDS, 16B per lane; LDS dest is wave-uniform base (HW adds lane*16)
__device__ __forceinline__ void gload_lds16(const void* g, void* l) {
  __builtin_amdgcn_global_load_lds((const __attribute__((address_space(1))) void*)g,
                                   (__attribute__((address_space(3))) void*)l,
                                   16, 0, 0);
}

__device__ __forceinline__ bf16x8v cvt_bf16x8(f32x4v a, f32x4v b) {
  bf16x8v r;
  r[0] = (__bf16)a[0]; r[1] = (__bf16)a[1]; r[2] = (__bf16)a[2]; r[3] = (__bf16)a[3];
  r[4] = (__bf16)b[0]; r[5] = (__bf16)b[1]; r[6] = (__bf16)b[2]; r[7] = (__bf16)b[3];
  return r;
}

// ---------------- prep: toep bf16 [1024,1024] + Wcat bf16 [128,1024] -------------------
__global__ __launch_bounds__(256) void prep_kernel(const float* __restrict__ W1,
                                                   const float* __restrict__ Wslope,
                                                   const float* __restrict__ Wint,
                                                   __bf16* __restrict__ toep,
                                                   __bf16* __restrict__ Wcat) {
  int id = blockIdx.x * 256 + threadIdx.x;
  if (id < 1024 * 1024) {
    int i = id >> 10, j = id & 1023;
    int p = 1023 - i + j;
    float v = (p < 1024) ? W1[(size_t)(1023 - p) << 10] : W1[p - 1023];
    toep[id] = (__bf16)v;
  } else {
    int id2 = id - 1024 * 1024;
    int n = id2 >> 10, k = id2 & 1023;
    float v = (n < 64) ? Wslope[((size_t)n << 10) + k] : Wint[((size_t)(n - 64) << 10) + k];
    Wcat[id2] = (__bf16)v;
  }
}

// ---------------- GEMM1: q = relu([x|h] @ toep^T + b1) --------------------------------
// Round-0 proven 128x128/BK=32 bf16 structure; A fused from fp32 x/h via reg-staging:
// each lane loads 32B fp32 one kt ahead (global_load_dwordx4 x2 per row), converts,
// ds_write_b128 into the SAME linear bf16 layout round-0's DMA produced. B unchanged
// (global_load_lds DMA from toep). One barrier per kt; the barrier's vmcnt(0) drain
// guarantees both the B-DMA and the A regs.
__global__ __launch_bounds__(256) void gemm1_fused(const float* __restrict__ x,
                                                   const float* __restrict__ h,
                                                   const __bf16* __restrict__ toep,
                                                   const float* __restrict__ b1,
                                                   __bf16* __restrict__ q) {
  __shared__ __align__(16) __bf16 Ab[2][128 * 32];
  __shared__ __align__(16) __bf16 Bb[2][128 * 32];
  const int tid = threadIdx.x, wid = tid >> 6, lane = tid & 63;
  const int wrow = wid >> 1, wcol = wid & 1;
  // XCD swizzle (round-0 proven): XCD x gets m-tiles {x, 8+x, ...}, n-tiles consecutive.
  const int bid = blockIdx.x;
  const int xcd = bid & 7, j = bid >> 3;
  const int m0 = (((j >> 3) << 3) | xcd) << 7;   // m-tile 0..511
  const int n0 = (j & 7) << 7;                   // n-tile 0..7
  const int quad = lane >> 4, l15 = lane & 15;
  const int rl = lane >> 2, seg = lane & 3;      // 4 lanes/row, 16 rows per write/instr

  f32x4v acc[4][4] = {};
  f32x4v rA[4];                                  // rows rl, rl+16: 2x 32B fp32

  const int arow = m0 + wid * 32;
  const __bf16* gB = toep + (((size_t)(n0 + wid * 32 + rl)) << 10) + seg * 8;
  const size_t ROW16 = (size_t)16 << 10;

  auto loadA = [&](int kt) {
    const int k0 = kt << 5;
    const float* src; size_t ld;
    if (k0 < 64) { src = x + k0;      ld = 64;  }
    else         { src = h + k0 - 64; ld = 960; }
    const float* p0 = src + (size_t)(arow + rl) * ld + seg * 8;
    const float* p1 = src + (size_t)(arow + rl + 16) * ld + seg * 8;
    rA[0] = *(const f32x4v*)p0; rA[1] = *(const f32x4v*)(p0 + 4);
    rA[2] = *(const f32x4v*)p1; rA[3] = *(const f32x4v*)(p1 + 4);
  };
  auto writeA = [&](__bf16* la) {
    const int r0 = wid * 32 + rl;
    *(bf16x8v*)&la[r0 * 32 + seg * 8]        = cvt_bf16x8(rA[0], rA[1]);
    *(bf16x8v*)&la[(r0 + 16) * 32 + seg * 8] = cvt_bf16x8(rA[2], rA[3]);
  };
  auto stageB = [&](__bf16* lb) {
    const int rb = wid * 32;
    gload_lds16(gB,         &lb[rb * 32]);
    gload_lds16(gB + ROW16, &lb[(rb + 16) * 32]);
    gB += 32;
  };

  auto compute = [&](const __bf16* la, const __bf16* lb) {
    bf16x8v af[4], bfr[4];
#pragma unroll
    for (int r = 0; r < 4; ++r)
      af[r] = *(const bf16x8v*)&la[(wrow * 64 + r * 16 + l15) * 32 + quad * 8];
#pragma unroll
    for (int c = 0; c < 4; ++c)
      bfr[c] = *(const bf16x8v*)&lb[(wcol * 64 + c * 16 + l15) * 32 + quad * 8];
#pragma unroll
    for (int r = 0; r < 4; ++r)
#pragma unroll
      for (int c = 0; c < 4; ++c)
        acc[r][c] = __builtin_amdgcn_mfma_f32_16x16x32_bf16(af[r], bfr[c], acc[r][c], 0, 0, 0);
  };

  // prologue: A(0) regs -> Ab0; B(0) DMA -> Bb0; A(1) in flight
  loadA(0);
  stageB(Bb[0]);
  writeA(Ab[0]);            // vmcnt wait keeps the 2 B-DMA in flight (issued after loads)
  loadA(1);

  for (int kt = 0; kt < 32; ++kt) {
    const int cur = kt & 1;
    __syncthreads();        // drains B-DMA(kt); Ab[cur] writes visible; guards [cur^1] reuse
    if (kt < 31) {
      stageB(Bb[cur ^ 1]);  // DMA kt+1
      writeA(Ab[cur ^ 1]);  // rA holds A(kt+1), already drained by the barrier
      if (kt < 30) loadA(kt + 2);
    }
    compute(Ab[cur], Bb[cur]);
  }

  // epilogue: C/D col=lane&15, row=quad*4+e
#pragma unroll
  for (int c = 0; c < 4; ++c) {
    int col = n0 + wcol * 64 + c * 16 + l15;
    float bias = b1[col];
#pragma unroll
    for (int r = 0; r < 4; ++r)
#pragma unroll
      for (int e = 0; e < 4; ++e) {
        int row = m0 + wrow * 64 + r * 16 + quad * 4 + e;
        q[((size_t)row << 10) + col] = (__bf16)fmaxf(acc[r][c][e] + bias, 0.0f);
      }
  }
}

// ---------------- GEMM2: [slope|intercept] = act(q @ Wcat^T + bias) -------------------
// Clone of the proven round-0 gemm1 structure: 128x128 tile (N=128 = all of Wcat, so
// no n-tiling), BK=32, dbuf DMA, unroll-2 K loop, wave tile 64x64. 512 blocks.
__global__ __launch_bounds__(256) void gemm2_v2(const __bf16* __restrict__ q,
                                                const __bf16* __restrict__ Wcat,
                                                const float* __restrict__ b_slope,
                                                const float* __restrict__ b_int,
                                                float* __restrict__ out) {
  __shared__ __align__(16) __bf16 Ab0[128 * 32], Ab1[128 * 32];
  __shared__ __align__(16) __bf16 Bb0[128 * 32], Bb1[128 * 32];
  const int tid = threadIdx.x, wid = tid >> 6, lane = tid & 63;
  const int wrow = wid >> 1, wcol = wid & 1;
  const int m0 = blockIdx.x << 7;                // 512 blocks x 128 rows
  const int quad = lane >> 4, l15 = lane & 15;
  const int rl = lane >> 2, seg = lane & 3;      // DMA: 4 lanes/row, 16 rows/instr

  f32x4v acc[4][4] = {};

  const __bf16* gA = q    + (((size_t)(m0 + wid * 32 + rl)) << 10) + seg * 8;
  const __bf16* gB = Wcat + (((size_t)(wid * 32 + rl)) << 10) + seg * 8;
  const size_t ROW16 = (size_t)16 << 10;

  auto stage = [&](__bf16* la, __bf16* lb) {
    int rb = wid * 32;
    gload_lds16(gA,         &la[rb * 32]);
    gload_lds16(gA + ROW16, &la[(rb + 16) * 32]);
    gload_lds16(gB,         &lb[rb * 32]);
    gload_lds16(gB + ROW16, &lb[(rb + 16) * 32]);
    gA += 32; gB += 32;
  };

  auto compute = [&](const __bf16* la, const __bf16* lb) {
    bf16x8v af[4], bfr[4];
#pragma unroll
    for (int r = 0; r < 4; ++r)
      af[r] = *(const bf16x8v*)&la[(wrow * 64 + r * 16 + l15) * 32 + quad * 8];
#pragma unroll
    for (int c = 0; c < 4; ++c)
      bfr[c] = *(const bf16x8v*)&lb[(wcol * 64 + c * 16 + l15) * 32 + quad * 8];
#pragma unroll
    for (int r = 0; r < 4; ++r)
#pragma unroll
      for (int c = 0; c < 4; ++c)
        acc[r][c] = __builtin_amdgcn_mfma_f32_16x16x32_bf16(af[r], bfr[c], acc[r][c], 0, 0, 0);
  };

  stage(Ab0, Bb0);                               // kt = 0
  for (int kt = 0; kt < 32; kt += 2) {
    __syncthreads();                             // drains DMA into buf0; guards buf1 reuse
    stage(Ab1, Bb1);                             // kt+1
    compute(Ab0, Bb0);
    __syncthreads();                             // drains DMA into buf1; guards buf0 reuse
    if (kt < 30) stage(Ab0, Bb0);                // kt+2
    compute(Ab1, Bb1);
  }

  // epilogue: col = wcol*64 + c*16 + l15 in [0,128); tanh half / linear half
#pragma unroll
  for (int c = 0; c < 4; ++c) {
    int col = wcol * 64 + c * 16 + l15;          // wave-uniform split at 64 (wcol)
    float bias = (col < 64) ? b_slope[col] : b_int[col - 64];
#pragma unroll
    for (int r = 0; r < 4; ++r)
#pragma unroll
      for (int e = 0; e < 4; ++e) {
        int row = m0 + wrow * 64 + r * 16 + quad * 4 + e;
        float v = acc[r][c][e] + bias;
        if (col < 64) {
          float xc = fminf(fmaxf(v, -15.f), 15.f);
          float t = __expf(2.f * xc);
          out[(size_t)row * 64 + col] = (t - 1.f) / (t + 1.f);   // tanh
        } else {
          out[(size_t)4194304 + (size_t)row * 64 + (col - 64)] = v;
        }
      }
  }
}

extern "C" void kernel_launch(void* const* d_in, const int* in_sizes, int n_in,
                              void* d_out, int out_size, void* d_ws, size_t ws_size,
                              hipStream_t stream) {
  const float* x  = (const float*)d_in[0];
  const float* h  = (const float*)d_in[1];
  const float* W1 = (const float*)d_in[2];
  const float* b1 = (const float*)d_in[3];
  const float* Ws = (const float*)d_in[4];
  const float* bs = (const float*)d_in[5];
  const float* Wi = (const float*)d_in[6];
  const float* bi = (const float*)d_in[7];
  char* ws = (char*)d_ws;

  const size_t SZ_Q    = 134217728;   // q    bf16 [65536,1024]
  const size_t SZ_TOEP = 2097152;     // toep bf16 [1024,1024]

  __bf16* q    = (__bf16*)ws;
  __bf16* toep = (__bf16*)(ws + SZ_Q);
  __bf16* Wcat = (__bf16*)(ws + SZ_Q + SZ_TOEP);

  hipLaunchKernelGGL(prep_kernel, dim3(4608), dim3(256), 0, stream, W1, Ws, Wi, toep, Wcat);
  hipLaunchKernelGGL(gemm1_fused, dim3(4096), dim3(256), 0, stream, x, h, toep, b1, q);
  hipLaunchKernelGGL(gemm2_v2,    dim3(512),  dim3(256), 0, stream, q, Wcat, bs, bi,
                     (float*)d_out);
}